// Round 12
// baseline (51.167 us; speedup 1.0000x reference)
//
#include <hip/hip_runtime.h>
#include <hip/hip_bf16.h>
#include <float.h>

#define B 16
#define H 32
#define HKV 8
#define G 4
#define D 128
#define LMAX 2048
#define SCALE 0.08838834764831844f  // 1/sqrt(128)
#define THR 8.0f                    // defer-max rescale threshold (T13)

// Kernel 1: ONE WAVE per (b, kv-head, split), single pass, online softmax.
// 2 row-groups x 32 lanes (lane owns d-chunk ln*4..+4 of K/V row). Per
// iteration each group processes one row: K float4 + V float4 per lane,
// dot via 5-step width-32 butterfly, running (m,l,O) in registers with
// defer-max. Explicit 2-stage pipeline: data(t+1) + pointers(t+2) prefetched
// each iteration (clamped indices -> branchless, loads always in-bounds).
// Epilogue merges the 2 groups fully in-register (mask-32 butterfly).
// LDS = pointer tables only (~1KB); ~95 VGPR + launch_bounds(64,4) -> 4
// waves/SIMD; CHUNK=32 -> ~4200 active waves = 16/CU.
// part_o : [B][HKV][NSPLIT][G][D]  (written only if split non-empty)
// part_ml: [B][HKV][NSPLIT][G][2]  (m, sum_exp; always written)
template <int CHUNK>
__global__ __launch_bounds__(64, 4) void attn_partial(
    const float* __restrict__ q,
    const float* __restrict__ kin,
    const float* __restrict__ vin,
    const float* __restrict__ kc,
    const float* __restrict__ vc,
    const int*  __restrict__ slot_mapping,
    const int*  __restrict__ active_slots,
    const int*  __restrict__ context_lens,
    float* __restrict__ part_o,
    float* __restrict__ part_ml)
{
    constexpr int NSPLIT = LMAX / CHUNK;
    const int tid   = threadIdx.x;            // 0..63
    const int split = blockIdx.x % NSPLIT;
    const int h     = (blockIdx.x / NSPLIT) % HKV;
    const int b     = blockIdx.x / (NSPLIT * HKV);

    const int ctx   = context_lens[b];
    const int start = split * CHUNK;
    int nvalid = ctx - start;
    if (nvalid > CHUNK) nvalid = CHUNK;

    const size_t pbase = ((size_t)(b * HKV + h) * NSPLIT + split) * G;

    if (nvalid <= 0) {
        if (tid < G * 2) part_ml[pbase * 2 + tid] = (tid & 1) ? 0.f : -FLT_MAX;
        return;
    }

    __shared__ const float* kp[CHUNK];   // wave-private pointer tables
    __shared__ const float* vp[CHUNK];

    // ---- resolve slot -> row pointers
    for (int li = tid; li < nvalid; li += 64) {
        const int s = active_slots[b * LMAX + start + li];
        int ov = -1;
#pragma unroll
        for (int j = 0; j < 16; ++j)
            if (slot_mapping[j] == s) ov = j;
        kp[li] = (ov >= 0) ? kin + ((size_t)ov * HKV + h) * D : kc + ((size_t)s * HKV + h) * D;
        vp[li] = (ov >= 0) ? vin + ((size_t)ov * HKV + h) * D : vc + ((size_t)s * HKV + h) * D;
    }
    __syncthreads();   // single wave: LDS write->read ordering

    const int grp2 = tid >> 5;    // row-parity group
    const int ln   = tid & 31;    // d-chunk
    const int nv1  = nvalid - 1;

    // q fragments (pre-scaled): qv[g] = floats [ln*4, ln*4+4)
    float4 qv[G];
#pragma unroll
    for (int g = 0; g < G; ++g) {
        float4 t = *(const float4*)(q + ((size_t)(b * H + h * G + g)) * D + ln * 4);
        qv[g] = make_float4(t.x * SCALE, t.y * SCALE, t.z * SCALE, t.w * SCALE);
    }

    float m0 = -1e30f, m1 = -1e30f, m2 = -1e30f, m3 = -1e30f;
    float l0 = 0.f, l1 = 0.f, l2 = 0.f, l3 = 0.f;
    float4 o0 = {0,0,0,0}, o1 = {0,0,0,0}, o2 = {0,0,0,0}, o3 = {0,0,0,0};

    const int iters = (nvalid + 1) >> 1;

    // pipeline prologue: data(0) issued, pointers(1) in regs
    int ra = grp2;     ra = (ra <= nv1) ? ra : nv1;
    int rb = 2 + grp2; rb = (rb <= nv1) ? rb : nv1;
    const float* kB = kp[rb];
    const float* vB = vp[rb];
    float4 ka = *(const float4*)(kp[ra] + ln * 4);
    float4 va = *(const float4*)(vp[ra] + ln * 4);

    for (int it = 0; it < iters; ++it) {
        // issue next-iter data loads + fetch next-next pointers (clamped)
        float4 kb = *(const float4*)(kB + ln * 4);
        float4 vb = *(const float4*)(vB + ln * 4);
        int rn = (it + 2) * 2 + grp2; rn = (rn <= nv1) ? rn : nv1;
        const float* kN = kp[rn];
        const float* vN = vp[rn];

        // compute current row r = it*2 + grp2
        const int r = it * 2 + grp2;
        float pd0 = ka.x * qv[0].x + ka.y * qv[0].y + ka.z * qv[0].z + ka.w * qv[0].w;
        float pd1 = ka.x * qv[1].x + ka.y * qv[1].y + ka.z * qv[1].z + ka.w * qv[1].w;
        float pd2 = ka.x * qv[2].x + ka.y * qv[2].y + ka.z * qv[2].z + ka.w * qv[2].w;
        float pd3 = ka.x * qv[3].x + ka.y * qv[3].y + ka.z * qv[3].z + ka.w * qv[3].w;
#pragma unroll
        for (int msk = 1; msk < 32; msk <<= 1) {
            pd0 += __shfl_xor(pd0, msk);
            pd1 += __shfl_xor(pd1, msk);
            pd2 += __shfl_xor(pd2, msk);
            pd3 += __shfl_xor(pd3, msk);
        }
        const bool valid = (r < nvalid);
        const float s0 = valid ? pd0 : -1e30f;
        const float s1 = valid ? pd1 : -1e30f;
        const float s2 = valid ? pd2 : -1e30f;
        const float s3 = valid ? pd3 : -1e30f;

        // defer-max rescale (rare; first valid row enters with l=o=0)
        if (s0 > m0 + THR) {
            const float sc = __expf(m0 - s0); l0 *= sc; m0 = s0;
            o0.x *= sc; o0.y *= sc; o0.z *= sc; o0.w *= sc;
        }
        if (s1 > m1 + THR) {
            const float sc = __expf(m1 - s1); l1 *= sc; m1 = s1;
            o1.x *= sc; o1.y *= sc; o1.z *= sc; o1.w *= sc;
        }
        if (s2 > m2 + THR) {
            const float sc = __expf(m2 - s2); l2 *= sc; m2 = s2;
            o2.x *= sc; o2.y *= sc; o2.z *= sc; o2.w *= sc;
        }
        if (s3 > m3 + THR) {
            const float sc = __expf(m3 - s3); l3 *= sc; m3 = s3;
            o3.x *= sc; o3.y *= sc; o3.z *= sc; o3.w *= sc;
        }

        const float p0 = __expf(s0 - m0);   // invalid row: underflows to 0
        const float p1 = __expf(s1 - m1);   // (or killed by w=0 merge below)
        const float p2 = __expf(s2 - m2);
        const float p3 = __expf(s3 - m3);
        l0 += p0; l1 += p1; l2 += p2; l3 += p3;
        o0.x += p0 * va.x; o0.y += p0 * va.y; o0.z += p0 * va.z; o0.w += p0 * va.w;
        o1.x += p1 * va.x; o1.y += p1 * va.y; o1.z += p1 * va.z; o1.w += p1 * va.w;
        o2.x += p2 * va.x; o2.y += p2 * va.y; o2.z += p2 * va.z; o2.w += p2 * va.w;
        o3.x += p3 * va.x; o3.y += p3 * va.y; o3.z += p3 * va.z; o3.w += p3 * va.w;

        ka = kb; va = vb; kB = kN; vB = vN;
    }

    // ---- merge the two row-groups fully in-register (mask-32 butterfly)
    {
        const float M0 = fmaxf(m0, __shfl_xor(m0, 32));
        const float M1 = fmaxf(m1, __shfl_xor(m1, 32));
        const float M2 = fmaxf(m2, __shfl_xor(m2, 32));
        const float M3 = fmaxf(m3, __shfl_xor(m3, 32));
        const float w0 = __expf(m0 - M0);   // empty group: exp(-1e30-M)=0
        const float w1 = __expf(m1 - M1);
        const float w2 = __expf(m2 - M2);
        const float w3 = __expf(m3 - M3);
        l0 *= w0; l1 *= w1; l2 *= w2; l3 *= w3;
        l0 += __shfl_xor(l0, 32); l1 += __shfl_xor(l1, 32);
        l2 += __shfl_xor(l2, 32); l3 += __shfl_xor(l3, 32);
        o0.x *= w0; o0.y *= w0; o0.z *= w0; o0.w *= w0;
        o1.x *= w1; o1.y *= w1; o1.z *= w1; o1.w *= w1;
        o2.x *= w2; o2.y *= w2; o2.z *= w2; o2.w *= w2;
        o3.x *= w3; o3.y *= w3; o3.z *= w3; o3.w *= w3;
        o0.x += __shfl_xor(o0.x, 32); o0.y += __shfl_xor(o0.y, 32);
        o0.z += __shfl_xor(o0.z, 32); o0.w += __shfl_xor(o0.w, 32);
        o1.x += __shfl_xor(o1.x, 32); o1.y += __shfl_xor(o1.y, 32);
        o1.z += __shfl_xor(o1.z, 32); o1.w += __shfl_xor(o1.w, 32);
        o2.x += __shfl_xor(o2.x, 32); o2.y += __shfl_xor(o2.y, 32);
        o2.z += __shfl_xor(o2.z, 32); o2.w += __shfl_xor(o2.w, 32);
        o3.x += __shfl_xor(o3.x, 32); o3.y += __shfl_xor(o3.y, 32);
        o3.z += __shfl_xor(o3.z, 32); o3.w += __shfl_xor(o3.w, 32);
        m0 = M0; m1 = M1; m2 = M2; m3 = M3;
    }

    // ---- store: group 0 lanes write heads 0,1; group 1 lanes heads 2,3
    if (grp2 == 0) {
        *(float4*)(part_o + (pbase + 0) * D + ln * 4) = o0;
        *(float4*)(part_o + (pbase + 1) * D + ln * 4) = o1;
    } else {
        *(float4*)(part_o + (pbase + 2) * D + ln * 4) = o2;
        *(float4*)(part_o + (pbase + 3) * D + ln * 4) = o3;
    }
    if (tid == 0) {
        *(float4*)&part_ml[pbase * 2 + 0] = make_float4(m0, l0, m1, l1);
        *(float4*)&part_ml[pbase * 2 + 4] = make_float4(m2, l2, m3, l3);
    }
}

// Kernel 2: merge nsplit partials per (b, h, g); 2-way split-parallel.
__global__ __launch_bounds__(256) void attn_reduce(
    const float* __restrict__ part_o,
    const float* __restrict__ part_ml,
    float* __restrict__ out,
    int nsplit)
{
    const int g = blockIdx.x & 3;
    const int h = (blockIdx.x >> 2) & 7;
    const int b = blockIdx.x >> 5;
    const int d  = threadIdx.x & 127;
    const int sp = threadIdx.x >> 7;

    __shared__ float mlds[64], llds[64];
    __shared__ float red[128];
    __shared__ float lred;
    const size_t base = (size_t)(b * HKV + h) * nsplit;

    for (int s = threadIdx.x; s < nsplit; s += 256) {
        mlds[s] = part_ml[((base + s) * G + g) * 2 + 0];
        llds[s] = part_ml[((base + s) * G + g) * 2 + 1];
    }
    __syncthreads();

    float M = -FLT_MAX;
    for (int s = 0; s < nsplit; ++s)
        if (llds[s] > 0.f) M = fmaxf(M, mlds[s]);

    float L = 0.f, acc = 0.f;
    for (int s = sp; s < nsplit; s += 2) {
        const float l = llds[s];
        if (l > 0.f) {
            const float e = __expf(mlds[s] - M);
            L += l * e;
            acc += e * part_o[((base + s) * G + g) * D + d];
        }
    }
    if (sp == 1) {
        red[d] = acc;
        if (d == 0) lred = L;
    }
    __syncthreads();
    if (sp == 0) {
        acc += red[d];
        L   += lred;
        out[((size_t)(b * H) + h * G + g) * D + d] = acc / (L > 0.f ? L : 1.f);
    }
}

extern "C" void kernel_launch(void* const* d_in, const int* in_sizes, int n_in,
                              void* d_out, int out_size, void* d_ws, size_t ws_size,
                              hipStream_t stream) {
    const float* q  = (const float*)d_in[0];
    const float* k  = (const float*)d_in[1];
    const float* v  = (const float*)d_in[2];
    const float* kc = (const float*)d_in[3];
    const float* vc = (const float*)d_in[4];
    const int* slot_mapping = (const int*)d_in[5];
    const int* active_slots = (const int*)d_in[6];
    const int* context_lens = (const int*)d_in[7];
    float* out = (float*)d_out;

    const size_t perSplit = (size_t)B * HKV * (G * D + G * 2) * sizeof(float);
    int nsplit = 8;
    if (ws_size >= 64 * perSplit)      nsplit = 64;
    else if (ws_size >= 32 * perSplit) nsplit = 32;
    else if (ws_size >= 16 * perSplit) nsplit = 16;

    float* part_o  = (float*)d_ws;
    float* part_ml = part_o + (size_t)B * HKV * nsplit * G * D;

    if (nsplit == 64) {
        attn_partial<32><<<B * HKV * 64, 64, 0, stream>>>(
            q, k, v, kc, vc, slot_mapping, active_slots, context_lens, part_o, part_ml);
    } else if (nsplit == 32) {
        attn_partial<64><<<B * HKV * 32, 64, 0, stream>>>(
            q, k, v, kc, vc, slot_mapping, active_slots, context_lens, part_o, part_ml);
    } else if (nsplit == 16) {
        attn_partial<128><<<B * HKV * 16, 64, 0, stream>>>(
            q, k, v, kc, vc, slot_mapping, active_slots, context_lens, part_o, part_ml);
    } else {
        attn_partial<256><<<B * HKV * 8, 64, 0, stream>>>(
            q, k, v, kc, vc, slot_mapping, active_slots, context_lens, part_o, part_ml);
    }
    attn_reduce<<<B * HKV * G, 256, 0, stream>>>(part_o, part_ml, out, nsplit);
}